// Round 2
// baseline (668.252 us; speedup 1.0000x reference)
//
#include <hip/hip_runtime.h>
#include <hip/hip_bf16.h>
#include <math.h>

// NoisyTopkRouter: B=8 S=4096 D=4096 E=64 k=8
// rows = B*S = 32768. Combined GEMM: [rows, D] x [D, 2E] -> noisy logits,
// fused epilogue: softmax(full), ordered top-8, sparse softmax (gates).
// Output (FLOAT32): gates[rows*64] | ix[rows*8] | full[rows*64]

#define BM 64          // rows per block
#define KC 32          // k-chunk
#define D_DIM 4096
#define HS_STRIDE 68   // padded [KC][row] stride (mult of 4 for b128 align)
#define WS_STRIDE 132  // padded [KC][v] stride
#define NOISY_STRIDE 65

__device__ __forceinline__ float softplus_f(float x) {
    return fmaxf(x, 0.0f) + log1pf(expf(-fabsf(x)));
}

__global__ __launch_bounds__(256)
void router_kernel(const float* __restrict__ h,
                   const float* __restrict__ Ww,
                   const float* __restrict__ bw,
                   const float* __restrict__ Wn,
                   const float* __restrict__ bn,
                   const float* __restrict__ noise,
                   float* __restrict__ out_gates,
                   float* __restrict__ out_ix,
                   float* __restrict__ out_full)
{
    __shared__ __align__(16) float smem[KC * HS_STRIDE + KC * WS_STRIDE]; // 6400 floats = 25.6KB
    float* hs = smem;                    // [KC][HS_STRIDE]  (k-major, row minor)
    float* ws = smem + KC * HS_STRIDE;   // [KC][WS_STRIDE]  (k-major, vcol minor)

    const int t    = threadIdx.x;
    const int tr   = t & 15;    // row-group: rows tr*4 .. tr*4+3
    const int te   = t >> 4;    // col-group: vcols te*8 .. te*8+7 (experts te*4..te*4+3)
    const int row0 = blockIdx.x * BM;

    float acc[4][8];
#pragma unroll
    for (int i = 0; i < 4; ++i)
#pragma unroll
        for (int j = 0; j < 8; ++j) acc[i][j] = 0.0f;

    const int kk4 = (t & 7) * 4;  // k offset within chunk for staging
    const int rl  = t >> 3;       // 0..31

    for (int kc = 0; kc < D_DIM / KC; ++kc) {
        const int k0 = kc * KC;
        __syncthreads();
        // stage h: 64 rows x 32 k, store transposed hs[kk][row]
#pragma unroll
        for (int i = 0; i < 2; ++i) {
            const int r = rl + 32 * i;
            const float4 v = *reinterpret_cast<const float4*>(
                h + (size_t)(row0 + r) * D_DIM + k0 + kk4);
            hs[(kk4 + 0) * HS_STRIDE + r] = v.x;
            hs[(kk4 + 1) * HS_STRIDE + r] = v.y;
            hs[(kk4 + 2) * HS_STRIDE + r] = v.z;
            hs[(kk4 + 3) * HS_STRIDE + r] = v.w;
        }
        // stage W (interleaved: vcol = 2*expert + {0:Ww,1:Wn}), store ws[kk][v]
#pragma unroll
        for (int i = 0; i < 4; ++i) {
            const int v = rl + 32 * i;
            const float* src = (v & 1) ? Wn : Ww;
            const float4 wv = *reinterpret_cast<const float4*>(
                src + (size_t)(v >> 1) * D_DIM + k0 + kk4);
            ws[(kk4 + 0) * WS_STRIDE + v] = wv.x;
            ws[(kk4 + 1) * WS_STRIDE + v] = wv.y;
            ws[(kk4 + 2) * WS_STRIDE + v] = wv.z;
            ws[(kk4 + 3) * WS_STRIDE + v] = wv.w;
        }
        __syncthreads();

        // per-chunk partial accumulators (two-level sum: ~3e-7 abs error vs ~1.5e-6 flat)
        float c[4][8];
#pragma unroll
        for (int i = 0; i < 4; ++i)
#pragma unroll
            for (int j = 0; j < 8; ++j) c[i][j] = 0.0f;

#pragma unroll 8
        for (int kk = 0; kk < KC; ++kk) {
            const float4 a  = *reinterpret_cast<const float4*>(&hs[kk * HS_STRIDE + tr * 4]);
            const float4 b0 = *reinterpret_cast<const float4*>(&ws[kk * WS_STRIDE + te * 8]);
            const float4 b1 = *reinterpret_cast<const float4*>(&ws[kk * WS_STRIDE + te * 8 + 4]);
            const float av[4] = {a.x, a.y, a.z, a.w};
            const float bv[8] = {b0.x, b0.y, b0.z, b0.w, b1.x, b1.y, b1.z, b1.w};
#pragma unroll
            for (int i = 0; i < 4; ++i)
#pragma unroll
                for (int j = 0; j < 8; ++j) c[i][j] += av[i] * bv[j];
        }
#pragma unroll
        for (int i = 0; i < 4; ++i)
#pragma unroll
            for (int j = 0; j < 8; ++j) acc[i][j] += c[i][j];
    }

    __syncthreads();

    // compute noisy = logits_w + bw + noise * softplus(logits_n + bn); store [expert][lrow]
    float* noisy_s = smem;
#pragma unroll
    for (int jj = 0; jj < 4; ++jj) {
        const int ex = te * 4 + jj;
        const float bwv = bw[ex];
        const float bnv = bn[ex];
#pragma unroll
        for (int i = 0; i < 4; ++i) {
            const int lrow = tr * 4 + i;
            const int grow = row0 + lrow;
            const float lw = acc[i][2 * jj]     + bwv;
            const float ln = acc[i][2 * jj + 1] + bnv;
            const float nz = noise[(size_t)grow * 64 + ex];
            noisy_s[ex * NOISY_STRIDE + lrow] = lw + nz * softplus_f(ln);
        }
    }
    __syncthreads();

    // epilogue: one wave per 16 rows; lane = expert
    const int lane = t & 63;
    const int wv   = t >> 6;
    for (int q = 0; q < 16; ++q) {
        const int lrow = wv * 16 + q;
        const int grow = row0 + lrow;
        const float v = noisy_s[lane * NOISY_STRIDE + lrow];

        float cur = v;
        float m8 = 0.0f;
        int winIdx = 0;
        bool picked = false;
#pragma unroll
        for (int r = 0; r < 8; ++r) {
            float bvv = cur;
            int   bi  = lane;
#pragma unroll
            for (int off = 32; off; off >>= 1) {
                const float ov = __shfl_xor(bvv, off);
                const int   oi = __shfl_xor(bi, off);
                if (ov > bvv || (ov == bvv && oi < bi)) { bvv = ov; bi = oi; }
            }
            if (r == 0) m8 = bvv;          // global max (top-1)
            if (lane == r) winIdx = bi;    // r-th winner index lives on lane r
            if (lane == bi) { picked = true; cur = -INFINITY; }
        }

        const float pf = expf(v - m8);
        const float pg = picked ? pf : 0.0f;
        float sf = pf, sg = pg;
#pragma unroll
        for (int off = 32; off; off >>= 1) {
            sf += __shfl_xor(sf, off);
            sg += __shfl_xor(sg, off);
        }

        out_full [(size_t)grow * 64 + lane] = pf / sf;
        out_gates[(size_t)grow * 64 + lane] = pg / sg;
        if (lane < 8) out_ix[(size_t)grow * 8 + lane] = (float)winIdx;
    }
}

extern "C" void kernel_launch(void* const* d_in, const int* in_sizes, int n_in,
                              void* d_out, int out_size, void* d_ws, size_t ws_size,
                              hipStream_t stream) {
    const float* h  = (const float*)d_in[0];
    const float* Ww = (const float*)d_in[1];
    const float* bw = (const float*)d_in[2];
    const float* Wn = (const float*)d_in[3];
    const float* bn = (const float*)d_in[4];
    const float* nz = (const float*)d_in[5];

    const int rows = in_sizes[5] / 64;   // B*S = 32768

    float* out = (float*)d_out;
    float* og = out;                                        // gates [rows*64]
    float* oi = out + (size_t)rows * 64;                    // ix    [rows*8]
    float* of = out + (size_t)rows * 64 + (size_t)rows * 8; // full  [rows*64]

    hipLaunchKernelGGL(router_kernel, dim3(rows / BM), dim3(256), 0, stream,
                       h, Ww, bw, Wn, bn, nz, og, oi, of);
}

// Round 4
// 390.624 us; speedup vs baseline: 1.7107x; 1.7107x over previous
//
#include <hip/hip_runtime.h>
#include <hip/hip_bf16.h>
#include <math.h>

// NoisyTopkRouter: rows=32768, D=4096, E=64, k=8.
// MFMA bf16x3-exact-split GEMM with zero-C main term + Kahan fold (ix-rank
// precision ~6e-8), fused noisy epilogue + top-8 + two softmaxes.
// Output (fp32): gates[rows*64] | ix[rows*8] | full[rows*64]

typedef __attribute__((ext_vector_type(8))) short bf16x8;
typedef __attribute__((ext_vector_type(4))) float f32x4;

#define BM 64
#define KC 32
#define D_DIM 4096
#define NSTEP (D_DIM / KC)   // 128

// LDS byte offsets: 3 h-planes [64 rows][64B], 3 W-planes [128 rows][64B]
#define HA0 0
#define HA1 4096
#define HA2 8192
#define WB0 12288
#define WB1 20480
#define WB2 28672
#define SMEM_BYTES 36864

__device__ __forceinline__ float softplus_f(float x) {
    return fmaxf(x, 0.0f) + log1pf(expf(-fabsf(x)));
}

// Exact 3-way truncation split: x == f(u0) + f(u1) + f(u2), each bf16-representable.
__device__ __forceinline__ void split3(float x, unsigned &u0, unsigned &u1, unsigned &u2) {
    unsigned ux = __float_as_uint(x);
    u0 = ux & 0xffff0000u;
    float r = x - __uint_as_float(u0);
    unsigned ur = __float_as_uint(r);
    u1 = ur & 0xffff0000u;
    float r2 = r - __uint_as_float(u1);
    u2 = __float_as_uint(r2);          // low 16 bits zero by construction
}

__device__ __forceinline__ int swz16(int row, int ch) {   // 16B-chunk XOR swizzle
    return (ch ^ ((row >> 1) & 3)) & 3;
}

__global__ __launch_bounds__(256)
void router_kernel(const float* __restrict__ h,
                   const float* __restrict__ Ww,
                   const float* __restrict__ bw,
                   const float* __restrict__ Wn,
                   const float* __restrict__ bn,
                   const float* __restrict__ noise,
                   float* __restrict__ out_gates,
                   float* __restrict__ out_ix,
                   float* __restrict__ out_full)
{
    __shared__ __align__(16) char smem[SMEM_BYTES];

    const int t    = threadIdx.x;
    const int row0 = blockIdx.x * BM;

    // ---- staging geometry ----
    const int hrow = t >> 2, hch = t & 3;
    const float* hp = h + (size_t)(row0 + hrow) * D_DIM + hch * 8;
    const int wrow = t >> 1, wk = (t & 1) * 16;
    const float* wp = ((wrow < 64) ? (Ww + (size_t)wrow * D_DIM)
                                   : (Wn + (size_t)(wrow - 64) * D_DIM)) + wk;

    const int hwb = hrow * 64 + swz16(hrow, hch) * 16;
    const int wb1 = wrow * 64 + swz16(wrow, (wk >> 3)) * 16;
    const int wb2 = wrow * 64 + swz16(wrow, (wk >> 3) + 1) * 16;

    // ---- compute geometry ----
    const int lane = t & 63, wv = t >> 6;
    const int c  = lane & 15, kg = lane >> 4;
    const int arow = wv * 16 + c;
    const int aoff = arow * 64 + swz16(arow, kg) * 16;

    f32x4 sA[8], cA[8], accB[8];
#pragma unroll
    for (int j = 0; j < 8; ++j) {
        sA[j] = (f32x4)0.0f; cA[j] = (f32x4)0.0f; accB[j] = (f32x4)0.0f;
    }

    // prologue loads (step 0)
    float4 hv0 = *reinterpret_cast<const float4*>(hp);
    float4 hv1 = *reinterpret_cast<const float4*>(hp + 4);
    float4 wq0 = *reinterpret_cast<const float4*>(wp);
    float4 wq1 = *reinterpret_cast<const float4*>(wp + 4);
    float4 wq2 = *reinterpret_cast<const float4*>(wp + 8);
    float4 wq3 = *reinterpret_cast<const float4*>(wp + 12);

    for (int kc = 0; kc < NSTEP; ++kc) {
        __syncthreads();   // prior step's LDS reads complete

        // ---- convert staged regs -> 3 bf16 planes ----
        {
            float f[8] = {hv0.x, hv0.y, hv0.z, hv0.w, hv1.x, hv1.y, hv1.z, hv1.w};
            unsigned p0[4], p1[4], p2[4];
#pragma unroll
            for (int i = 0; i < 4; ++i) {
                unsigned x0, x1, x2, y0, y1, y2;
                split3(f[2 * i], x0, x1, x2);
                split3(f[2 * i + 1], y0, y1, y2);
                p0[i] = y0 | (x0 >> 16);
                p1[i] = y1 | (x1 >> 16);
                p2[i] = (y2 & 0xffff0000u) | (x2 >> 16);
            }
            *reinterpret_cast<uint4*>(smem + HA0 + hwb) = make_uint4(p0[0], p0[1], p0[2], p0[3]);
            *reinterpret_cast<uint4*>(smem + HA1 + hwb) = make_uint4(p1[0], p1[1], p1[2], p1[3]);
            *reinterpret_cast<uint4*>(smem + HA2 + hwb) = make_uint4(p2[0], p2[1], p2[2], p2[3]);
        }
        {
            float f[16] = {wq0.x, wq0.y, wq0.z, wq0.w, wq1.x, wq1.y, wq1.z, wq1.w,
                           wq2.x, wq2.y, wq2.z, wq2.w, wq3.x, wq3.y, wq3.z, wq3.w};
            unsigned p0[8], p1[8], p2[8];
#pragma unroll
            for (int i = 0; i < 8; ++i) {
                unsigned x0, x1, x2, y0, y1, y2;
                split3(f[2 * i], x0, x1, x2);
                split3(f[2 * i + 1], y0, y1, y2);
                p0[i] = y0 | (x0 >> 16);
                p1[i] = y1 | (x1 >> 16);
                p2[i] = (y2 & 0xffff0000u) | (x2 >> 16);
            }
            *reinterpret_cast<uint4*>(smem + WB0 + wb1) = make_uint4(p0[0], p0[1], p0[2], p0[3]);
            *reinterpret_cast<uint4*>(smem + WB0 + wb2) = make_uint4(p0[4], p0[5], p0[6], p0[7]);
            *reinterpret_cast<uint4*>(smem + WB1 + wb1) = make_uint4(p1[0], p1[1], p1[2], p1[3]);
            *reinterpret_cast<uint4*>(smem + WB1 + wb2) = make_uint4(p1[4], p1[5], p1[6], p1[7]);
            *reinterpret_cast<uint4*>(smem + WB2 + wb1) = make_uint4(p2[0], p2[1], p2[2], p2[3]);
            *reinterpret_cast<uint4*>(smem + WB2 + wb2) = make_uint4(p2[4], p2[5], p2[6], p2[7]);
        }
        __syncthreads();   // planes ready

        // issue next step's global loads
        if (kc + 1 < NSTEP) {
            const float* hq = hp + (kc + 1) * KC;
            const float* wq = wp + (kc + 1) * KC;
            hv0 = *reinterpret_cast<const float4*>(hq);
            hv1 = *reinterpret_cast<const float4*>(hq + 4);
            wq0 = *reinterpret_cast<const float4*>(wq);
            wq1 = *reinterpret_cast<const float4*>(wq + 4);
            wq2 = *reinterpret_cast<const float4*>(wq + 8);
            wq3 = *reinterpret_cast<const float4*>(wq + 12);
        }

        // ---- MFMA compute ----
        const bf16x8 A0 = *reinterpret_cast<const bf16x8*>(smem + HA0 + aoff);
        const bf16x8 A1 = *reinterpret_cast<const bf16x8*>(smem + HA1 + aoff);
        const bf16x8 A2 = *reinterpret_cast<const bf16x8*>(smem + HA2 + aoff);
#pragma unroll
        for (int j = 0; j < 8; ++j) {
            const int brow = j * 16 + c;
            const int boff = brow * 64 + swz16(brow, kg) * 16;
            const bf16x8 B0 = *reinterpret_cast<const bf16x8*>(smem + WB0 + boff);
            const bf16x8 B1 = *reinterpret_cast<const bf16x8*>(smem + WB1 + boff);
            const bf16x8 B2 = *reinterpret_cast<const bf16x8*>(smem + WB2 + boff);

            // main term: per-step zero-C MFMA, Kahan fold (IEEE-strict, no fast-math)
            f32x4 st = __builtin_amdgcn_mfma_f32_16x16x32_bf16(A0, B0, (f32x4)0.0f, 0, 0, 0);
#pragma unroll
            for (int e = 0; e < 4; ++e) {
                float y = st[e] - cA[j][e];
                float tt = sA[j][e] + y;
                cA[j][e] = (tt - sA[j][e]) - y;
                sA[j][e] = tt;
            }
            // small cross terms: plain chained accumulator (scale ~1e-3)
            accB[j] = __builtin_amdgcn_mfma_f32_16x16x32_bf16(A0, B1, accB[j], 0, 0, 0);
            accB[j] = __builtin_amdgcn_mfma_f32_16x16x32_bf16(A1, B0, accB[j], 0, 0, 0);
            accB[j] = __builtin_amdgcn_mfma_f32_16x16x32_bf16(A1, B1, accB[j], 0, 0, 0);
            accB[j] = __builtin_amdgcn_mfma_f32_16x16x32_bf16(A0, B2, accB[j], 0, 0, 0);
            accB[j] = __builtin_amdgcn_mfma_f32_16x16x32_bf16(A2, B0, accB[j], 0, 0, 0);
        }
    }

    __syncthreads();

    // ---- noisy logits -> LDS [expert][row] ----
    // C/D layout: col = lane&15, row = (lane>>4)*4 + reg
    float* noisy_s = reinterpret_cast<float*>(smem);   // [64][65]
#pragma unroll
    for (int j = 0; j < 4; ++j) {
        const int e = j * 16 + c;
        const float bwv = bw[e];
        const float bnv = bn[e];
#pragma unroll
        for (int r = 0; r < 4; ++r) {
            const int lrow = wv * 16 + kg * 4 + r;
            const int grow = row0 + lrow;
            const float lw = sA[j][r] + accB[j][r] + bwv;
            const float ln = sA[j + 4][r] + accB[j + 4][r] + bnv;
            const float nz = noise[(size_t)grow * 64 + e];
            noisy_s[e * 65 + lrow] = lw + nz * softplus_f(ln);
        }
    }
    __syncthreads();

    // ---- top-8 + softmaxes: one wave per 16 rows, lane = expert ----
    for (int q = 0; q < 16; ++q) {
        const int lrow = wv * 16 + q;
        const int grow = row0 + lrow;
        const float v = noisy_s[lane * 65 + lrow];

        float cur = v;
        float m8 = 0.0f;
        int winIdx = 0;
        bool picked = false;
#pragma unroll
        for (int r = 0; r < 8; ++r) {
            float bvv = cur;
            int   bi  = lane;
#pragma unroll
            for (int off = 32; off; off >>= 1) {
                const float ov = __shfl_xor(bvv, off);
                const int   oi = __shfl_xor(bi, off);
                if (ov > bvv || (ov == bvv && oi < bi)) { bvv = ov; bi = oi; }
            }
            if (r == 0) m8 = bvv;
            if (lane == r) winIdx = bi;
            if (lane == bi) { picked = true; cur = -INFINITY; }
        }

        const float pf = expf(v - m8);
        const float pg = picked ? pf : 0.0f;
        float sf = pf, sg = pg;
#pragma unroll
        for (int off = 32; off; off >>= 1) {
            sf += __shfl_xor(sf, off);
            sg += __shfl_xor(sg, off);
        }

        out_full [(size_t)grow * 64 + lane] = pf / sf;
        out_gates[(size_t)grow * 64 + lane] = pg / sg;
        if (lane < 8) out_ix[(size_t)grow * 8 + lane] = (float)winIdx;
    }
}

extern "C" void kernel_launch(void* const* d_in, const int* in_sizes, int n_in,
                              void* d_out, int out_size, void* d_ws, size_t ws_size,
                              hipStream_t stream) {
    const float* h  = (const float*)d_in[0];
    const float* Ww = (const float*)d_in[1];
    const float* bw = (const float*)d_in[2];
    const float* Wn = (const float*)d_in[3];
    const float* bn = (const float*)d_in[4];
    const float* nz = (const float*)d_in[5];

    const int rows = in_sizes[5] / 64;   // 32768

    float* out = (float*)d_out;
    float* og = out;
    float* oi = out + (size_t)rows * 64;
    float* of = out + (size_t)rows * 64 + (size_t)rows * 8;

    hipLaunchKernelGGL(router_kernel, dim3(rows / BM), dim3(256), 0, stream,
                       h, Ww, bw, Wn, bn, nz, og, oi, of);
}

// Round 5
// 309.307 us; speedup vs baseline: 2.1605x; 1.2629x over previous
//
#include <hip/hip_runtime.h>
#include <hip/hip_bf16.h>
#include <math.h>

// NoisyTopkRouter: rows=32768, D=4096, E=64, k=8.
// R5: W planes precomputed to d_ws (exact LDS image, swizzled); h staged raw
// fp32 via global_load_lds w/ pre-swizzled source; split3 at fragment read;
// 2x2 wave tiles; group-of-8 chained MFMA + Kahan fold.
// Output (fp32): gates[rows*64] | ix[rows*8] | full[rows*64]

typedef __attribute__((ext_vector_type(8))) short bf16x8;
typedef __attribute__((ext_vector_type(4))) float f32x4;
typedef unsigned int u32;

#define BM 64
#define D_DIM 4096
#define NSTEP 128
#define WSTEP_BYTES 24576   // per-step W image: 3 planes x 8KB

// LDS map (main loop)
#define HBUF0 0
#define HBUF1 8192
#define WBUF0 16384
#define WBUF1 40960
#define SMEM_BYTES 65536

__device__ __forceinline__ float softplus_f(float x) {
    return fmaxf(x, 0.0f) + log1pf(expf(-fabsf(x)));
}

// Exact 3-way truncation split: x == f(u0)+f(u1)+f(u2), each bf16-representable.
__device__ __forceinline__ void split3(float x, u32 &u0, u32 &u1, u32 &u2) {
    u32 ux = __float_as_uint(x);
    u0 = ux & 0xffff0000u;
    float r = x - __uint_as_float(u0);
    u32 ur = __float_as_uint(r);
    u1 = ur & 0xffff0000u;
    float r2 = r - __uint_as_float(u1);
    u2 = __float_as_uint(r2);      // low 16 bits zero by construction
}

__device__ __forceinline__ void gl16(void* lds, const void* g) {
    __builtin_amdgcn_global_load_lds(
        (const __attribute__((address_space(1))) u32*)g,
        (__attribute__((address_space(3))) u32*)lds, 16, 0, 0);
}

// ---- W pre-conversion: 3 bf16 planes, per-step 24KB LDS image, swizzled ----
// image[kc][p*8192 + vrow*64 + sc*16] = chunk (sc ^ ((vrow>>2)&3)) of plane p
__global__ __launch_bounds__(256)
void wconv_kernel(const float* __restrict__ Ww, const float* __restrict__ Wn,
                  char* __restrict__ Wp)
{
    const int bid = blockIdx.x;            // 256 blocks
    const int kc = bid >> 1, half = bid & 1;
    const int t = threadIdx.x;
    const int vrow = half * 64 + (t >> 2); // 0..127 (0-63=Ww, 64-127=Wn)
    const int c4 = t & 3;                  // 16B chunk (8 k-elements)
    const float* src = (vrow < 64) ? (Ww + (size_t)vrow * D_DIM)
                                   : (Wn + (size_t)(vrow - 64) * D_DIM);
    const float4 a = *reinterpret_cast<const float4*>(src + kc * 32 + c4 * 8);
    const float4 b = *reinterpret_cast<const float4*>(src + kc * 32 + c4 * 8 + 4);
    const float f[8] = {a.x, a.y, a.z, a.w, b.x, b.y, b.z, b.w};
    u32 p0[4], p1[4], p2[4];
#pragma unroll
    for (int i = 0; i < 4; ++i) {
        u32 x0, x1, x2, y0, y1, y2;
        split3(f[2 * i], x0, x1, x2);
        split3(f[2 * i + 1], y0, y1, y2);
        p0[i] = y0 | (x0 >> 16);
        p1[i] = y1 | (x1 >> 16);
        p2[i] = (y2 & 0xffff0000u) | (x2 >> 16);
    }
    const int sc = c4 ^ ((vrow >> 2) & 3);
    char* dst = Wp + (size_t)kc * WSTEP_BYTES + vrow * 64 + sc * 16;
    *reinterpret_cast<uint4*>(dst)          = make_uint4(p0[0], p0[1], p0[2], p0[3]);
    *reinterpret_cast<uint4*>(dst + 8192)   = make_uint4(p1[0], p1[1], p1[2], p1[3]);
    *reinterpret_cast<uint4*>(dst + 16384)  = make_uint4(p2[0], p2[1], p2[2], p2[3]);
}

__global__ __launch_bounds__(256, 2)
void router_kernel(const float* __restrict__ h,
                   const float* __restrict__ bw,
                   const float* __restrict__ bn,
                   const float* __restrict__ noise,
                   const char* __restrict__ Wp,
                   float* __restrict__ out_gates,
                   float* __restrict__ out_ix,
                   float* __restrict__ out_full)
{
    __shared__ __align__(16) char smem[SMEM_BYTES];

    const int t    = threadIdx.x;
    const int row0 = blockIdx.x * BM;
    const int lane = t & 63, w = t >> 6;
    const int c = lane & 15, kg = lane >> 4;
    const int wr = w >> 1, wc = w & 1;     // 2x2 wave grid: rows wr*32.., cols wc*64..

    // ---- staging geometry ----
    // h image[row*128 + sc*16] = fp32 chunk (sc ^ (row&7));  row_local = r*32+w*8+(l>>3)
    const int hl  = lane >> 3;                 // row-within-8 (== row_local & 7)
    const int hsc = (lane & 7) ^ hl;           // pre-swizzled source chunk
    const float* hsrc0 = h + (size_t)(row0 +      w * 8 + hl) * D_DIM + hsc * 4;
    const float* hsrc1 = h + (size_t)(row0 + 32 + w * 8 + hl) * D_DIM + hsc * 4;
    const int hdst0 = w * 1024;                // + r*4096 + buf base (wave-uniform)
    const int hdst1 = 4096 + w * 1024;
    const char* wsrc = Wp + w * 1024 + lane * 16;   // + kc*24576 + i*4096

    // ---- accumulators ----
    f32x4 grp[2][4], sA[2][4], cA[2][4], accB[2][4];
#pragma unroll
    for (int fi = 0; fi < 2; ++fi)
#pragma unroll
        for (int j = 0; j < 4; ++j) {
            grp[fi][j] = (f32x4)0.0f; sA[fi][j] = (f32x4)0.0f;
            cA[fi][j]  = (f32x4)0.0f; accB[fi][j] = (f32x4)0.0f;
        }

    // prologue: stage step 0 into buf 0
    {
        gl16(smem + HBUF0 + hdst0, hsrc0);
        gl16(smem + HBUF0 + hdst1, hsrc1);
#pragma unroll
        for (int i = 0; i < 6; ++i)
            gl16(smem + WBUF0 + i * 4096 + w * 1024, wsrc + i * 4096);
    }
    __syncthreads();   // compiler drains vmcnt before barrier

    int cur = 0;
    for (int kc = 0; kc < NSTEP; ++kc) {
        // stage next step into other buffer (async, in flight across compute)
        if (kc + 1 < NSTEP) {
            const int hb_n = (cur ^ 1) ? HBUF1 : HBUF0;
            const int wb_n = (cur ^ 1) ? WBUF1 : WBUF0;
            const size_t ho = (size_t)(kc + 1) * 32;
            gl16(smem + hb_n + hdst0, hsrc0 + ho);
            gl16(smem + hb_n + hdst1, hsrc1 + ho);
            const char* ws = wsrc + (size_t)(kc + 1) * WSTEP_BYTES;
#pragma unroll
            for (int i = 0; i < 6; ++i)
                gl16(smem + wb_n + i * 4096 + w * 1024, ws + i * 4096);
        }

        const int hb = cur ? HBUF1 : HBUF0;
        const int wb = cur ? WBUF1 : WBUF0;

        // ---- A fragments: read raw fp32 h, split3 in-register ----
        bf16x8 A0[2], A1[2], A2[2];
#pragma unroll
        for (int fi = 0; fi < 2; ++fi) {
            const int arow = wr * 32 + fi * 16 + c;
            const int s0 = ((kg * 2)     ^ (arow & 7)) * 16;
            const int s1 = ((kg * 2 + 1) ^ (arow & 7)) * 16;
            const float4 fa = *reinterpret_cast<const float4*>(smem + hb + arow * 128 + s0);
            const float4 fb = *reinterpret_cast<const float4*>(smem + hb + arow * 128 + s1);
            const float f[8] = {fa.x, fa.y, fa.z, fa.w, fb.x, fb.y, fb.z, fb.w};
            union { u32 u[4]; bf16x8 v; } q0, q1, q2;
#pragma unroll
            for (int i = 0; i < 4; ++i) {
                u32 x0, x1, x2, y0, y1, y2;
                split3(f[2 * i], x0, x1, x2);
                split3(f[2 * i + 1], y0, y1, y2);
                q0.u[i] = y0 | (x0 >> 16);
                q1.u[i] = y1 | (x1 >> 16);
                q2.u[i] = (y2 & 0xffff0000u) | (x2 >> 16);
            }
            A0[fi] = q0.v; A1[fi] = q1.v; A2[fi] = q2.v;
        }

        // ---- B fragments + MFMA ----
#pragma unroll
        for (int j = 0; j < 4; ++j) {
            const int brow = wc * 64 + j * 16 + c;
            const int bo = wb + brow * 64 + ((kg ^ ((brow >> 2) & 3)) * 16);
            const bf16x8 B0 = *reinterpret_cast<const bf16x8*>(smem + bo);
            const bf16x8 B1 = *reinterpret_cast<const bf16x8*>(smem + bo + 8192);
            const bf16x8 B2 = *reinterpret_cast<const bf16x8*>(smem + bo + 16384);
#pragma unroll
            for (int fi = 0; fi < 2; ++fi) {
                grp[fi][j]  = __builtin_amdgcn_mfma_f32_16x16x32_bf16(A0[fi], B0, grp[fi][j], 0, 0, 0);
                accB[fi][j] = __builtin_amdgcn_mfma_f32_16x16x32_bf16(A0[fi], B1, accB[fi][j], 0, 0, 0);
                accB[fi][j] = __builtin_amdgcn_mfma_f32_16x16x32_bf16(A1[fi], B0, accB[fi][j], 0, 0, 0);
                accB[fi][j] = __builtin_amdgcn_mfma_f32_16x16x32_bf16(A1[fi], B1, accB[fi][j], 0, 0, 0);
                accB[fi][j] = __builtin_amdgcn_mfma_f32_16x16x32_bf16(A0[fi], B2, accB[fi][j], 0, 0, 0);
                accB[fi][j] = __builtin_amdgcn_mfma_f32_16x16x32_bf16(A2[fi], B0, accB[fi][j], 0, 0, 0);
            }
        }

        // ---- fold group into Kahan sum every 8 steps ----
        if ((kc & 7) == 7) {
#pragma unroll
            for (int fi = 0; fi < 2; ++fi)
#pragma unroll
                for (int j = 0; j < 4; ++j) {
#pragma unroll
                    for (int e = 0; e < 4; ++e) {
                        float y  = grp[fi][j][e] - cA[fi][j][e];
                        float tt = sA[fi][j][e] + y;
                        cA[fi][j][e] = (tt - sA[fi][j][e]) - y;
                        sA[fi][j][e] = tt;
                    }
                    grp[fi][j] = (f32x4)0.0f;
                }
        }

        __syncthreads();   // next buffer fully staged, this buffer free
        cur ^= 1;
    }

    // ---- logits -> LDS (combine wc=0 (w) and wc=1 (n) halves) ----
    float* lw_s = reinterpret_cast<float*>(smem);            // [64][65]
    float* ln_s = reinterpret_cast<float*>(smem + 16640);    // [64][65]
#pragma unroll
    for (int fi = 0; fi < 2; ++fi)
#pragma unroll
        for (int j = 0; j < 4; ++j)
#pragma unroll
            for (int r = 0; r < 4; ++r) {
                const int rowl = wr * 32 + fi * 16 + kg * 4 + r;
                const int e = j * 16 + c;
                const float vsum = sA[fi][j][r] + accB[fi][j][r];
                (wc ? ln_s : lw_s)[rowl * 65 + e] = vsum;
            }
    __syncthreads();

    // ---- noisy + top-8 + softmaxes: wave w -> rows w*16..+16, lane = expert ----
    const float bwv = bw[lane];
    const float bnv = bn[lane];
    for (int q = 0; q < 16; ++q) {
        const int lrow = w * 16 + q;
        const int grow = row0 + lrow;
        const float lwv = lw_s[lrow * 65 + lane] + bwv;
        const float lnv = ln_s[lrow * 65 + lane] + bnv;
        const float nz  = noise[(size_t)grow * 64 + lane];
        const float v   = lwv + nz * softplus_f(lnv);

        float cur2 = v;
        float m8 = 0.0f;
        int winIdx = 0;
        bool picked = false;
#pragma unroll
        for (int r = 0; r < 8; ++r) {
            float bvv = cur2;
            int   bi  = lane;
#pragma unroll
            for (int off = 32; off; off >>= 1) {
                const float ov = __shfl_xor(bvv, off);
                const int   oi = __shfl_xor(bi, off);
                if (ov > bvv || (ov == bvv && oi < bi)) { bvv = ov; bi = oi; }
            }
            if (r == 0) m8 = bvv;
            if (lane == r) winIdx = bi;
            if (lane == bi) { picked = true; cur2 = -INFINITY; }
        }

        const float pf = expf(v - m8);
        const float pg = picked ? pf : 0.0f;
        float sf = pf, sg = pg;
#pragma unroll
        for (int off = 32; off; off >>= 1) {
            sf += __shfl_xor(sf, off);
            sg += __shfl_xor(sg, off);
        }

        out_full [(size_t)grow * 64 + lane] = pf / sf;
        out_gates[(size_t)grow * 64 + lane] = pg / sg;
        if (lane < 8) out_ix[(size_t)grow * 8 + lane] = (float)winIdx;
    }
}

extern "C" void kernel_launch(void* const* d_in, const int* in_sizes, int n_in,
                              void* d_out, int out_size, void* d_ws, size_t ws_size,
                              hipStream_t stream) {
    const float* h  = (const float*)d_in[0];
    const float* Ww = (const float*)d_in[1];
    const float* bw = (const float*)d_in[2];
    const float* Wn = (const float*)d_in[3];
    const float* bn = (const float*)d_in[4];
    const float* nz = (const float*)d_in[5];

    const int rows = in_sizes[5] / 64;   // 32768

    float* out = (float*)d_out;
    float* og = out;
    float* oi = out + (size_t)rows * 64;
    float* of = out + (size_t)rows * 64 + (size_t)rows * 8;

    char* Wp = (char*)d_ws;   // 128 steps * 24576 B = 3 MB

    hipLaunchKernelGGL(wconv_kernel, dim3(256), dim3(256), 0, stream, Ww, Wn, Wp);
    hipLaunchKernelGGL(router_kernel, dim3(rows / BM), dim3(256), 0, stream,
                       h, bw, bn, nz, Wp, og, oi, of);
}